// Round 7
// baseline (625.403 us; speedup 1.0000x reference)
//
#include <hip/hip_runtime.h>
#include <math.h>

// Problem constants (fixed by setup_inputs)
#define B_ 1024
#define N_ 1024      // K dimension of the GEMM
#define T_ 16
#define H_ 4096
#define M_ (T_*B_)   // 16384 rows, row = t*B_ + b
#define NHB2_ 128    // h-slices of 32

#define LOG2C 0.69314718055994530942f

typedef int      i32x4  __attribute__((ext_vector_type(4)));
typedef _Float16 f16x8  __attribute__((ext_vector_type(8)));
typedef float    f32x16 __attribute__((ext_vector_type(16)));

// ---------------- numerics helpers ----------------

// atan2(y, x) for x > 0 (guaranteed: wre = 1 + e*cos >= 0).
// deg-11 odd minimax + reciprocal range reduction; |err| ~1e-5.
// HW-validated rounds 6-20 (absmax at comparison floor).
__device__ __forceinline__ float atan2_pos(float y, float x) {
    float ay = fabsf(y);
    float mn = fminf(ay, x), mx = fmaxf(ay, x);
    float r  = __fdividef(mn, mx);        // in [0,1]
    float t  = r * r;
    float p  = fmaf(t, -0.0117212f, 0.05265332f);
    p = fmaf(t, p, -0.11643287f);
    p = fmaf(t, p,  0.19354346f);
    p = fmaf(t, p, -0.33262347f);
    p = fmaf(t, p,  0.99997726f);
    float a = r * p;
    a = (ay > x) ? (1.5707963267948966f - a) : a;
    return (y < 0.0f) ? -a : a;
}

// fast-path log_cosh (fast atan)
__device__ __forceinline__ void log_cosh_f(float zr, float zi, float& lr, float& li) {
    float s = (zr < 0.0f) ? -1.0f : 1.0f;
    float a = zr * s;                    // >= 0
    float c = zi * s;
    float e = __expf(-2.0f * a);         // in (0,1]
    float s2, c2;
    __sincosf(2.0f * c, &s2, &c2);
    float wre = fmaf(e, c2, 1.0f);       // >= 0 always
    float wim = -e * s2;
    float mag2 = fmaf(wre, wre, wim * wim);
    lr = a + 0.5f * __logf(mag2) - LOG2C;
    li = c + atan2_pos(wim, wre);
}

// fallback-path log_cosh (libm atan2)
__device__ __forceinline__ void log_cosh_c(float zr, float zi, float& lr, float& li) {
    float s = (zr < 0.0f) ? -1.0f : 1.0f;
    float a = zr * s;
    float c = zi * s;
    float e = __expf(-2.0f * a);
    float s2, c2;
    __sincosf(2.0f * c, &s2, &c2);
    float wre = fmaf(e, c2, 1.0f);
    float wim = -e * s2;
    float mag2 = fmaf(wre, wre, wim * wim);
    lr = a + 0.5f * __logf(mag2) - LOG2C;
    li = c + atan2f(wim, wre);
}

__device__ __forceinline__ void gll16(const void* g, void* l) {
    __builtin_amdgcn_global_load_lds(
        (const __attribute__((address_space(1))) unsigned int*)g,
        (__attribute__((address_space(3))) unsigned int*)l,
        16, 0, 0);
}

// =======================================================================
// FAST PATH (f16 MFMA, W-through-LDS hybrid GEMM, 64-row waves).
// r21 post-mortem of r20 (f16, 419 us): -33% MFMA bought only -12.5% time;
// MfmaUtil fell to 33.5 => MFMA pipe was not binding. Pipe accounting at
// 419 us: LDS read pipe 39% (1:1 ds_read:MFMA ratio -- the classic
// under-amortized tile), MFMA 26%, epilogue VALU ~13%. LDS is the top pipe.
// This round: DOUBLE the m-tile per wave (64 rows x 32 h, two 32-row
// sub-tiles sharing the same W fragments): the same 4 ds_read_b128 per
// k-step now feed 8 MFMAs (LDS/MFMA 1:2). Block covers 256 rows; grid
// halves to 64x128 -- total barrier/stage events halve too. Tile-1 rows
// are +32 in the pack layout => pA+512 bytes, L2-hot (128-block hs-group
// shares a 512 KB A slice). Accumulation order per output element is
// unchanged => bitwise-identical result to r20 (absmax 0.125).
// ws layout (bytes):
//   A16  [K/8][M] 16B chunks (8 f16 of consecutive k)   33.55 MB
//   Wr16,Wi16 [K/8][H] 16B chunks (f16, W^T)            2 x 8.39 MB
//   part float4[128][M]  33.55 MB ;  red float4[M]  0.26 MB
// =======================================================================

// --- prep A: gather + f16 convert. One thread = one 16B chunk (8 elems).
__global__ __launch_bounds__(256) void prep_A16(
    const float* __restrict__ x, const int* __restrict__ trans,
    signed char* __restrict__ A16)
{
    int ci = blockIdx.x * 256 + threadIdx.x;   // kc*M_ + row, kc in 0..127
    int row = ci & (M_ - 1);
    int kc  = ci >> 14;
    int t   = row >> 10, b = row & (B_ - 1);
    const int* __restrict__ trow = trans + t * N_ + kc * 8;
    const float* __restrict__ xr = x + (size_t)b * N_;
    alignas(16) _Float16 buf[8];
    #pragma unroll
    for (int j = 0; j < 8; j++) buf[j] = (_Float16)xr[trow[j]];
    *(uint4*)(A16 + (size_t)ci * 16) = *(uint4*)buf;
}

// --- prep W: transpose-pack + f16 convert. blockIdx.y: 0->Wr, 1->Wi.
__global__ __launch_bounds__(256) void prep_W16(
    const float* __restrict__ Wr, const float* __restrict__ Wi,
    signed char* __restrict__ Wr16, signed char* __restrict__ Wi16)
{
    int ci = blockIdx.x * 256 + threadIdx.x;   // kc*H_ + h, kc in 0..127
    int h  = ci & (H_ - 1);
    int kc = ci >> 12;
    const float* __restrict__ W = blockIdx.y ? Wi : Wr;
    signed char* __restrict__ D = blockIdx.y ? Wi16 : Wr16;
    alignas(16) _Float16 buf[8];
    #pragma unroll
    for (int j = 0; j < 8; j++)
        buf[j] = (_Float16)W[(size_t)(kc * 8 + j) * H_ + h];
    *(uint4*)(D + (size_t)ci * 16) = *(uint4*)buf;
}

// --- main f16 MFMA GEMM: W double-buffered through LDS, A batch-prefetched,
//     each wave owns TWO 32-row sub-tiles (W-fragment reuse).
// Structure: block = 4 waves x 64 rows = 256 rows x one 32-h slice; W staged
// into 2 x 16 KB LDS buffers per K=128 band (8 bands, 8 barriers; prefetch
// for band s+1 issued at TOP of band s so the barrier's vmcnt(0) drain is
// ~aged-out); A streams global->VGPR in per-band batches (2 band-parity
// slot sets x 2 sub-tiles).
// MFMA operands SWAPPED (A-op = W, B-op = xt): D[h(regs)][m(cols)] -- the
// h-reduction is in-lane adds + ONE shuffle; partial write is coalesced.
// Layouts (dtype-independent, HW-verified r8-20): A/B frag lane l holds
// 16B chunk k8=(l>>5), index (l&31); C/D col=lane&31,
// row=(reg&3)+8*(reg>>2)+4*(lane>>5) [m74/m101].
// Per ks (K=32): 4 ds_read_b128 + 8 MFMA (1:2); per band: 4 gll16 (W) +
// 16 A chunk loads. Guard: WRITE_SIZE ~33 MB means no spill.
__global__ __launch_bounds__(256, 3) void gemm_f16(
    const signed char* __restrict__ A16,
    const signed char* __restrict__ Wr16, const signed char* __restrict__ Wi16,
    const float* __restrict__ br, const float* __restrict__ bi,
    float4* __restrict__ part)
{
    // [buf(2)][arr(2)][q(16)][h(32)] 16B chunks
    __shared__ __align__(16) signed char sW[32768];

    const int tid  = threadIdx.x;
    const int l    = tid & 63;
    const int w    = tid >> 6;
    const int c32  = l & 31;
    const int half = l >> 5;
    const int bx   = blockIdx.x;
    const int hs   = bx & 127;       // 0..127  h-slice (fastest-varying)
    const int mb   = bx >> 7;        // 0..63   m-block of 256 rows
    const int m0   = mb * 256 + w * 64;   // wave's 64-row tile (2 x 32)
    const int rowA = m0 + c32;

    // A chunk pointer: slot p holds chunk band*16 + 2p + half, row rowA;
    // sub-tile 1 rows are +32 => +512 bytes in the [kc][row] pack.
    const signed char* pA = A16 + ((size_t)half * M_ + rowA) * 16;
    const size_t strA = (size_t)2 * M_ * 16;   // advance 2 k8-chunks

    const int q_lo = tid >> 5;      // 0..7 (staging k-chunk low bits)
    const int h_st = tid & 31;      // staging h index
    const size_t woff = ((size_t)q_lo * H_ + hs * 32 + h_st) * 16;
    const signed char* wsrc0 = Wr16 + woff;
    const signed char* wsrc1 = Wi16 + woff;
    const int ldst = tid * 16;      // LDS dest: uniform + lane*16
    const size_t WQ8 = (size_t)8 * H_ * 16;    // 8 k8-chunks of W

    f32x16 aR0 = {}, aI0 = {}, aR1 = {}, aI1 = {};

    // A slots: [band-parity][8] per sub-tile, batch-loaded one band ahead
    f16x8 aS0[2][8], aS1[2][8];

    // ---- prologue: band 0 A batch + band 0 W into buf 0
    #pragma unroll
    for (int p = 0; p < 8; p++) {
        aS0[0][p] = *(const f16x8*)pA;
        aS1[0][p] = *(const f16x8*)(pA + 512);
        pA += strA;
    }
    gll16(wsrc0,       sW + 0 * 4096 + ldst);   // arr0 q0..7
    gll16(wsrc0 + WQ8, sW + 1 * 4096 + ldst);   // arr0 q8..15
    gll16(wsrc1,       sW + 2 * 4096 + ldst);   // arr1 q0..7
    gll16(wsrc1 + WQ8, sW + 3 * 4096 + ldst);   // arr1 q8..15
    __syncthreads();

    const int lbase = half * 512 + c32 * 16;    // per-lane LDS read base
    const size_t WBAND = (size_t)16 * H_ * 16;  // per-band W bytes per array

    #pragma unroll
    for (int s = 0; s < 8; s++) {
        const int cur = s & 1;
        const int nxt = cur ^ 1;

        // ---- prefetch band s+1 FIRST: 4 gll16 -> other LDS buffer, plus
        //      its 16 A chunk loads -> other slot set. By the band-end
        //      barrier these are ~4 ks old => vmcnt(0) drain ~free.
        if (s < 7) {
            size_t wadd = (size_t)(s + 1) * WBAND;
            gll16(wsrc0 + wadd,       sW + nxt * 16384 + 0 * 4096 + ldst);
            gll16(wsrc0 + wadd + WQ8, sW + nxt * 16384 + 1 * 4096 + ldst);
            gll16(wsrc1 + wadd,       sW + nxt * 16384 + 2 * 4096 + ldst);
            gll16(wsrc1 + wadd + WQ8, sW + nxt * 16384 + 3 * 4096 + ldst);
            #pragma unroll
            for (int p = 0; p < 8; p++) {
                aS0[nxt][p] = *(const f16x8*)pA;
                aS1[nxt][p] = *(const f16x8*)(pA + 512);
                pA += strA;
            }
        }

        // ---- 4 k-steps (K=32 each) from buf[cur]; 4 ds_read feed 8 MFMA
        #pragma unroll
        for (int ks = 0; ks < 4; ks++) {
            int off = cur * 16384 + ks * 2048 + lbase;   // q = ks*4 + 2j + half
            f16x8 wr0 = *(const f16x8*)&sW[off];                  // arr0 j0
            f16x8 wr1 = *(const f16x8*)&sW[off + 1024];           // arr0 j1
            f16x8 wi0 = *(const f16x8*)&sW[off + 8192];           // arr1 j0
            f16x8 wi1 = *(const f16x8*)&sW[off + 8192 + 1024];    // arr1 j1
            // swapped operands: D[h][m] += W^T[h][k] * xt[m][k]
            aR0 = __builtin_amdgcn_mfma_f32_32x32x16_f16(wr0, aS0[cur][ks*2+0], aR0, 0, 0, 0);
            aI0 = __builtin_amdgcn_mfma_f32_32x32x16_f16(wi0, aS0[cur][ks*2+0], aI0, 0, 0, 0);
            aR1 = __builtin_amdgcn_mfma_f32_32x32x16_f16(wr0, aS1[cur][ks*2+0], aR1, 0, 0, 0);
            aI1 = __builtin_amdgcn_mfma_f32_32x32x16_f16(wi0, aS1[cur][ks*2+0], aI1, 0, 0, 0);
            aR0 = __builtin_amdgcn_mfma_f32_32x32x16_f16(wr1, aS0[cur][ks*2+1], aR0, 0, 0, 0);
            aI0 = __builtin_amdgcn_mfma_f32_32x32x16_f16(wi1, aS0[cur][ks*2+1], aI0, 0, 0, 0);
            aR1 = __builtin_amdgcn_mfma_f32_32x32x16_f16(wr1, aS1[cur][ks*2+1], aR1, 0, 0, 0);
            aI1 = __builtin_amdgcn_mfma_f32_32x32x16_f16(wi1, aS1[cur][ks*2+1], aI1, 0, 0, 0);
        }
        if (s < 7) __syncthreads();
    }

    // ---- epilogue: lane = one output row per sub-tile; regs = 16 h values.
    // acc IS t directly (f32 accumulate). br/bi loaded once, used by both
    // sub-tiles. Per sub-tile: in-lane sum then ONE shuffle.
    const int hbase = hs * 32 + 4 * half;
    float pr0 = 0.f, pi0 = 0.f, nr0 = 0.f, ni0 = 0.f;
    float pr1 = 0.f, pi1 = 0.f, nr1 = 0.f, ni1 = 0.f;
    #pragma unroll
    for (int reg = 0; reg < 16; reg++) {
        int h = hbase + (reg & 3) + 8 * (reg >> 2);
        float brv = br[h], biv = bi[h];
        float lr1, li1, lr2, li2;
        // sub-tile 0
        log_cosh_f(aR0[reg] + brv, aI0[reg] + biv, lr1, li1);
        log_cosh_f(brv - aR0[reg], biv - aI0[reg], lr2, li2);
        pr0 += lr1; pi0 += li1; nr0 += lr2; ni0 += li2;
        // sub-tile 1
        log_cosh_f(aR1[reg] + brv, aI1[reg] + biv, lr1, li1);
        log_cosh_f(brv - aR1[reg], biv - aI1[reg], lr2, li2);
        pr1 += lr1; pi1 += li1; nr1 += lr2; ni1 += li2;
    }
    pr0 += __shfl_xor(pr0, 32, 64);
    pi0 += __shfl_xor(pi0, 32, 64);
    nr0 += __shfl_xor(nr0, 32, 64);
    ni0 += __shfl_xor(ni0, 32, 64);
    pr1 += __shfl_xor(pr1, 32, 64);
    pi1 += __shfl_xor(pi1, 32, 64);
    nr1 += __shfl_xor(nr1, 32, 64);
    ni1 += __shfl_xor(ni1, 32, 64);
    if (half == 0) {
        // coalesced: 32 lanes write 512B; each (hs,row) written exactly once
        part[(size_t)hs * M_ + m0 + c32]      = make_float4(pr0, pi0, nr0, ni0);
        part[(size_t)hs * M_ + m0 + 32 + c32] = make_float4(pr1, pi1, nr1, ni1);
    }
}

// --- reduce the 128 h-slice partials per row ---
__global__ __launch_bounds__(64) void reduce_hb(
    const float4* __restrict__ part, float4* __restrict__ red)
{
    int row = blockIdx.x * 64 + threadIdx.x;
    float a0 = 0.f, a1 = 0.f, a2 = 0.f, a3 = 0.f;
    #pragma unroll 8
    for (int hb = 0; hb < NHB2_; hb++) {
        float4 v = part[(size_t)hb * M_ + row];
        a0 += v.x; a1 += v.y; a2 += v.z; a3 += v.w;
    }
    red[row] = make_float4(a0, a1, a2, a3);
}

// --- final logsumexp over 32 complex values per batch element ---
__global__ __launch_bounds__(64) void lse_final(
    const float4* __restrict__ red, float* __restrict__ out, int mode)
{
    int b = blockIdx.x * 64 + threadIdx.x;
    float re[32], im[32];
    #pragma unroll
    for (int t = 0; t < T_; t++) {
        float4 v = red[t * B_ + b];
        re[t]      = v.x; im[t]      = v.y;
        re[16 + t] = v.z; im[16 + t] = v.w;
    }
    float m = re[0];
    #pragma unroll
    for (int k = 1; k < 32; k++) m = fmaxf(m, re[k]);
    float Sr = 0.f, Si = 0.f;
    #pragma unroll
    for (int k = 0; k < 32; k++) {
        float mag = expf(re[k] - m);
        float s, c;
        sincosf(im[k], &s, &c);   // |im| can be tens of rad: libm reduction
        Sr = fmaf(mag, c, Sr);
        Si = fmaf(mag, s, Si);
    }
    float ore = 0.5f * logf(fmaf(Sr, Sr, Si * Si)) + m;
    float oim = atan2f(Si, Sr);
    if (mode == 0) out[b] = ore;
    else { out[b] = ore; out[B_ + b] = oim; }
}

// =======================================================================
// FALLBACK PATH — round-4 fp32 kernels (verified passing), used only if
// ws_size is too small for the packs.
// =======================================================================
#define FBM 128
#define FBH 64
#define FHC 4
#define FHBG (H_/(FBH*FHC))
#define FBK 16
#define FASTR 132
#define FPS (FHBG*M_)

__global__ __launch_bounds__(256, 3) void gemm_epi_fb(
    const float* __restrict__ x, const int* __restrict__ trans,
    const float* __restrict__ Wr, const float* __restrict__ Wi,
    const float* __restrict__ br, const float* __restrict__ bi,
    float* __restrict__ part)
{
    __shared__ float As[FBK * FASTR];
    __shared__ float Brs[FBK * FBH];
    __shared__ float Bis[FBK * FBH];

    const int tid = threadIdx.x;
    const int tx = tid & 15;
    const int ty = tid >> 4;
    const int hbg = blockIdx.x;
    const int m0 = blockIdx.y * FBM;
    const int t_band = m0 >> 10;
    const int* __restrict__ trow = trans + t_band * N_;

    float pr[8] = {}, pi[8] = {}, nr[8] = {}, ni[8] = {};

    for (int hc = 0; hc < FHC; hc++) {
        const int h0 = (hbg * FHC + hc) * FBH;
        float accre[8][4] = {}, accim[8][4] = {};
        for (int k0 = 0; k0 < N_; k0 += FBK) {
            #pragma unroll
            for (int p = 0; p < 8; p++) {
                int idx = tid + p * 256;
                int kk = idx & 15, r = idx >> 4;
                int b = (m0 + r) & (B_ - 1);
                As[kk * FASTR + r] = x[(size_t)b * N_ + trow[k0 + kk]];
            }
            {
                int r = tid >> 4, c4 = tid & 15;
                *(float4*)(Brs + r * FBH + c4 * 4) =
                    *(const float4*)(Wr + (size_t)(k0 + r) * H_ + h0 + c4 * 4);
                *(float4*)(Bis + r * FBH + c4 * 4) =
                    *(const float4*)(Wi + (size_t)(k0 + r) * H_ + h0 + c4 * 4);
            }
            __syncthreads();
            #pragma unroll
            for (int k = 0; k < FBK; k++) {
                float a[8], wr[4], wi[4];
                *(float4*)&a[0]  = *(float4*)&As[k * FASTR + ty * 8];
                *(float4*)&a[4]  = *(float4*)&As[k * FASTR + ty * 8 + 4];
                *(float4*)&wr[0] = *(float4*)&Brs[k * FBH + tx * 4];
                *(float4*)&wi[0] = *(float4*)&Bis[k * FBH + tx * 4];
                #pragma unroll
                for (int i = 0; i < 8; i++)
                    #pragma unroll
                    for (int j = 0; j < 4; j++) {
                        accre[i][j] = fmaf(a[i], wr[j], accre[i][j]);
                        accim[i][j] = fmaf(a[i], wi[j], accim[i][j]);
                    }
            }
            __syncthreads();
        }
        float brv[4], biv[4];
        #pragma unroll
        for (int j = 0; j < 4; j++) {
            brv[j] = br[h0 + tx * 4 + j];
            biv[j] = bi[h0 + tx * 4 + j];
        }
        #pragma unroll
        for (int i = 0; i < 8; i++)
            #pragma unroll
            for (int j = 0; j < 4; j++) {
                float tr = accre[i][j], ti = accim[i][j];
                float lr, li;
                log_cosh_c(tr + brv[j], ti + biv[j], lr, li);
                pr[i] += lr; pi[i] += li;
                log_cosh_c(brv[j] - tr, biv[j] - ti, lr, li);
                nr[i] += lr; ni[i] += li;
            }
    }
    #pragma unroll
    for (int i = 0; i < 8; i++) {
        float a0 = pr[i], a1 = pi[i], a2 = nr[i], a3 = ni[i];
        #pragma unroll
        for (int off = 1; off < 16; off <<= 1) {
            a0 += __shfl_xor(a0, off, 64);
            a1 += __shfl_xor(a1, off, 64);
            a2 += __shfl_xor(a2, off, 64);
            a3 += __shfl_xor(a3, off, 64);
        }
        if (tx == 0) {
            int row = m0 + ty * 8 + i;
            part[0 * FPS + hbg * M_ + row] = a0;
            part[1 * FPS + hbg * M_ + row] = a1;
            part[2 * FPS + hbg * M_ + row] = a2;
            part[3 * FPS + hbg * M_ + row] = a3;
        }
    }
}

__global__ __launch_bounds__(256) void sum_lse_fb(
    const float* __restrict__ part, float* __restrict__ out, int mode)
{
    int b = blockIdx.x * 256 + threadIdx.x;
    float re[32], im[32];
    #pragma unroll
    for (int t = 0; t < T_; t++) {
        int row = t * B_ + b;
        float a0 = 0.f, a1 = 0.f, a2 = 0.f, a3 = 0.f;
        for (int hb = 0; hb < FHBG; hb++) {
            a0 += part[0 * FPS + hb * M_ + row];
            a1 += part[1 * FPS + hb * M_ + row];
            a2 += part[2 * FPS + hb * M_ + row];
            a3 += part[3 * FPS + hb * M_ + row];
        }
        re[t]      = a0; im[t]      = a1;
        re[16 + t] = a2; im[16 + t] = a3;
    }
    float m = re[0];
    #pragma unroll
    for (int k = 1; k < 32; k++) m = fmaxf(m, re[k]);
    float Sr = 0.f, Si = 0.f;
    #pragma unroll
    for (int k = 0; k < 32; k++) {
        float mag = expf(re[k] - m);
        float s, c;
        sincosf(im[k], &s, &c);
        Sr = fmaf(mag, c, Sr);
        Si = fmaf(mag, s, Si);
    }
    float ore = 0.5f * logf(fmaf(Sr, Sr, Si * Si)) + m;
    float oim = atan2f(Si, Sr);
    if (mode == 0) out[b] = ore;
    else { out[b] = ore; out[B_ + b] = oim; }
}

// =======================================================================

extern "C" void kernel_launch(void* const* d_in, const int* in_sizes, int n_in,
                              void* d_out, int out_size, void* d_ws, size_t ws_size,
                              hipStream_t stream) {
    const float *x = nullptr, *Wr = nullptr, *Wi = nullptr, *br = nullptr, *bi = nullptr;
    const int *trans = nullptr;
    for (int i = 0; i < n_in; i++) {
        int s = in_sizes[i];
        if (s == B_ * N_ && !x)            x  = (const float*)d_in[i];
        else if (s == N_ * H_)             { if (!Wr) Wr = (const float*)d_in[i];
                                             else if (!Wi) Wi = (const float*)d_in[i]; }
        else if (s == H_)                  { if (!br) br = (const float*)d_in[i];
                                             else if (!bi) bi = (const float*)d_in[i]; }
        else if (s == T_ * N_ && !trans)   trans = (const int*)d_in[i];
    }
    if (!x)     x     = (const float*)d_in[0];
    if (!Wr)    Wr    = (const float*)d_in[1];
    if (!Wi)    Wi    = (const float*)d_in[2];
    if (!br)    br    = (const float*)d_in[3];
    if (!bi)    bi    = (const float*)d_in[4];
    if (!trans) trans = (const int*)d_in[5];

    float* out = (float*)d_out;
    const int mode = (out_size == B_) ? 0 : 1;

    const size_t NEED = (size_t)2 * M_ * N_          // A16 (f16)
                      + (size_t)4 * N_ * H_          // Wr16+Wi16 (f16)
                      + (size_t)NHB2_ * M_ * 16      // float4 partials
                      + (size_t)M_ * 16;             // float4 reduced

    if (ws_size >= NEED) {
        signed char* A16  = (signed char*)d_ws;
        signed char* Wr16 = A16  + (size_t)2 * M_ * N_;
        signed char* Wi16 = Wr16 + (size_t)2 * N_ * H_;
        float4* part = (float4*)(Wi16 + (size_t)2 * N_ * H_);
        float4* red  = part + (size_t)NHB2_ * M_;

        prep_A16<<<(M_ * (N_ / 8)) / 256, 256, 0, stream>>>(x, trans, A16);
        dim3 gw((N_ / 8) * H_ / 256, 2);
        prep_W16<<<gw, 256, 0, stream>>>(Wr, Wi, Wr16, Wi16);
        gemm_f16<<<64 * 128, 256, 0, stream>>>(A16, Wr16, Wi16,
                                               br, bi, part);
        reduce_hb<<<M_ / 64, 64, 0, stream>>>(part, red);
        lse_final<<<B_ / 64, 64, 0, stream>>>(red, out, mode);
    } else {
        float* part = (float*)d_ws;
        dim3 grid(FHBG, M_ / FBM);
        gemm_epi_fb<<<grid, 256, 0, stream>>>(x, trans, Wr, Wi, br, bi, part);
        sum_lse_fb<<<B_ / 256, 256, 0, stream>>>(part, out, mode);
    }
}

// Round 8
// 574.293 us; speedup vs baseline: 1.0890x; 1.0890x over previous
//
#include <hip/hip_runtime.h>
#include <math.h>

// Problem constants (fixed by setup_inputs)
#define B_ 1024
#define N_ 1024      // K dimension of the GEMM
#define T_ 16
#define H_ 4096
#define M_ (T_*B_)   // 16384 rows, row = t*B_ + b
#define NHB2_ 128    // h-slices of 32

#define LOG2C 0.69314718055994530942f

typedef int      i32x4  __attribute__((ext_vector_type(4)));
typedef _Float16 f16x8  __attribute__((ext_vector_type(8)));
typedef float    f32x16 __attribute__((ext_vector_type(16)));

// ---------------- numerics helpers ----------------

// atan2(y, x) for x > 0 (guaranteed: wre = 1 + e*cos >= 0).
// deg-11 odd minimax + reciprocal range reduction; |err| ~1e-5.
// HW-validated rounds 6-21 (absmax at comparison floor).
__device__ __forceinline__ float atan2_pos(float y, float x) {
    float ay = fabsf(y);
    float mn = fminf(ay, x), mx = fmaxf(ay, x);
    float r  = __fdividef(mn, mx);        // in [0,1]
    float t  = r * r;
    float p  = fmaf(t, -0.0117212f, 0.05265332f);
    p = fmaf(t, p, -0.11643287f);
    p = fmaf(t, p,  0.19354346f);
    p = fmaf(t, p, -0.33262347f);
    p = fmaf(t, p,  0.99997726f);
    float a = r * p;
    a = (ay > x) ? (1.5707963267948966f - a) : a;
    return (y < 0.0f) ? -a : a;
}

// fast-path log_cosh (fast atan)
__device__ __forceinline__ void log_cosh_f(float zr, float zi, float& lr, float& li) {
    float s = (zr < 0.0f) ? -1.0f : 1.0f;
    float a = zr * s;                    // >= 0
    float c = zi * s;
    float e = __expf(-2.0f * a);         // in (0,1]
    float s2, c2;
    __sincosf(2.0f * c, &s2, &c2);
    float wre = fmaf(e, c2, 1.0f);       // >= 0 always
    float wim = -e * s2;
    float mag2 = fmaf(wre, wre, wim * wim);
    lr = a + 0.5f * __logf(mag2) - LOG2C;
    li = c + atan2_pos(wim, wre);
}

// fallback-path log_cosh (libm atan2)
__device__ __forceinline__ void log_cosh_c(float zr, float zi, float& lr, float& li) {
    float s = (zr < 0.0f) ? -1.0f : 1.0f;
    float a = zr * s;
    float c = zi * s;
    float e = __expf(-2.0f * a);
    float s2, c2;
    __sincosf(2.0f * c, &s2, &c2);
    float wre = fmaf(e, c2, 1.0f);
    float wim = -e * s2;
    float mag2 = fmaf(wre, wre, wim * wim);
    lr = a + 0.5f * __logf(mag2) - LOG2C;
    li = c + atan2f(wim, wre);
}

__device__ __forceinline__ void gll16(const void* g, void* l) {
    __builtin_amdgcn_global_load_lds(
        (const __attribute__((address_space(1))) unsigned int*)g,
        (__attribute__((address_space(3))) unsigned int*)l,
        16, 0, 0);
}

// =======================================================================
// FAST PATH (f16 MFMA, W-through-LDS hybrid GEMM, 64-row waves, JIT A).
// r22 post-mortem of r21: the 64-row tile was right but HAND-BATCHED A
// slot arrays (aS0[2][8]+aS1[2][8] = 128 VGPRs) spilled (WRITE 33->537 MB,
// 463 us). r20's counters showed VGPR=48: the compiler had collapsed the
// batch into JIT loads with its own pipelining -- explicit slots are pure
// register waste. This round keeps the 64-row tile (4 ds_read_b128 feed
// 8 MFMAs, 1:2 -- halving the LDS pipe that r20 identified as top pipe at
// 39%) but loads A JUST-IN-TIME in the k-step loop via one incrementing
// pointer (chunk = 2i+half is a single strided stream; stride 2*M_*16).
// Compiler hoists as registers permit. Register math: 64 acc + 16 W frag
// + ~16 A transient + addr ~= 115 < 170 cap. Guard: WRITE_SIZE ~33 MB.
// Accumulation order per output element unchanged => bitwise-identical
// result (absmax 0.125).
// ws layout (bytes):
//   A16  [K/8][M] 16B chunks (8 f16 of consecutive k)   33.55 MB
//   Wr16,Wi16 [K/8][H] 16B chunks (f16, W^T)            2 x 8.39 MB
//   part float4[128][M]  33.55 MB ;  red float4[M]  0.26 MB
// =======================================================================

// --- prep A: gather + f16 convert. One thread = one 16B chunk (8 elems).
__global__ __launch_bounds__(256) void prep_A16(
    const float* __restrict__ x, const int* __restrict__ trans,
    signed char* __restrict__ A16)
{
    int ci = blockIdx.x * 256 + threadIdx.x;   // kc*M_ + row, kc in 0..127
    int row = ci & (M_ - 1);
    int kc  = ci >> 14;
    int t   = row >> 10, b = row & (B_ - 1);
    const int* __restrict__ trow = trans + t * N_ + kc * 8;
    const float* __restrict__ xr = x + (size_t)b * N_;
    alignas(16) _Float16 buf[8];
    #pragma unroll
    for (int j = 0; j < 8; j++) buf[j] = (_Float16)xr[trow[j]];
    *(uint4*)(A16 + (size_t)ci * 16) = *(uint4*)buf;
}

// --- prep W: transpose-pack + f16 convert. blockIdx.y: 0->Wr, 1->Wi.
__global__ __launch_bounds__(256) void prep_W16(
    const float* __restrict__ Wr, const float* __restrict__ Wi,
    signed char* __restrict__ Wr16, signed char* __restrict__ Wi16)
{
    int ci = blockIdx.x * 256 + threadIdx.x;   // kc*H_ + h, kc in 0..127
    int h  = ci & (H_ - 1);
    int kc = ci >> 12;
    const float* __restrict__ W = blockIdx.y ? Wi : Wr;
    signed char* __restrict__ D = blockIdx.y ? Wi16 : Wr16;
    alignas(16) _Float16 buf[8];
    #pragma unroll
    for (int j = 0; j < 8; j++)
        buf[j] = (_Float16)W[(size_t)(kc * 8 + j) * H_ + h];
    *(uint4*)(D + (size_t)ci * 16) = *(uint4*)buf;
}

// --- main f16 MFMA GEMM: W double-buffered through LDS; each wave owns
//     TWO 32-row sub-tiles (W-fragment reuse); A loaded JIT from global.
// Structure: block = 4 waves x 64 rows = 256 rows x one 32-h slice; W
// staged into 2 x 16 KB LDS buffers per K=128 band (8 bands, 8 barriers;
// prefetch for band s+1 issued at TOP of band s so the barrier's vmcnt(0)
// drain is ~aged-out).
// MFMA operands SWAPPED (A-op = W, B-op = xt): D[h(regs)][m(cols)] -- the
// h-reduction is in-lane adds + ONE shuffle; partial write is coalesced.
// Layouts (dtype-independent, HW-verified r8-21): A/B frag lane l holds
// 16B chunk k8=(l>>5), index (l&31); C/D col=lane&31,
// row=(reg&3)+8*(reg>>2)+4*(lane>>5) [m74/m101].
// Per ks (K=32): 4 ds_read_b128 + 4 global 16B (A JIT) + 8 MFMA.
__global__ __launch_bounds__(256, 3) void gemm_f16(
    const signed char* __restrict__ A16,
    const signed char* __restrict__ Wr16, const signed char* __restrict__ Wi16,
    const float* __restrict__ br, const float* __restrict__ bi,
    float4* __restrict__ part)
{
    // [buf(2)][arr(2)][q(16)][h(32)] 16B chunks
    __shared__ __align__(16) signed char sW[32768];

    const int tid  = threadIdx.x;
    const int l    = tid & 63;
    const int w    = tid >> 6;
    const int c32  = l & 31;
    const int half = l >> 5;
    const int bx   = blockIdx.x;
    const int hs   = bx & 127;       // 0..127  h-slice (fastest-varying)
    const int mb   = bx >> 7;        // 0..63   m-block of 256 rows
    const int m0   = mb * 256 + w * 64;   // wave's 64-row tile (2 x 32)
    const int rowA = m0 + c32;

    // A stream: lane l reads chunks 2i+half (i=0..63), rows rowA / rowA+32.
    const signed char* pA = A16 + ((size_t)half * M_ + rowA) * 16;
    const size_t strA = (size_t)2 * M_ * 16;   // advance 2 k8-chunks

    const int q_lo = tid >> 5;      // 0..7 (staging k-chunk low bits)
    const int h_st = tid & 31;      // staging h index
    const size_t woff = ((size_t)q_lo * H_ + hs * 32 + h_st) * 16;
    const signed char* wsrc0 = Wr16 + woff;
    const signed char* wsrc1 = Wi16 + woff;
    const int ldst = tid * 16;      // LDS dest: uniform + lane*16
    const size_t WQ8 = (size_t)8 * H_ * 16;    // 8 k8-chunks of W

    f32x16 aR0 = {}, aI0 = {}, aR1 = {}, aI1 = {};

    // ---- prologue: band 0 W into buf 0
    gll16(wsrc0,       sW + 0 * 4096 + ldst);   // arr0 q0..7
    gll16(wsrc0 + WQ8, sW + 1 * 4096 + ldst);   // arr0 q8..15
    gll16(wsrc1,       sW + 2 * 4096 + ldst);   // arr1 q0..7
    gll16(wsrc1 + WQ8, sW + 3 * 4096 + ldst);   // arr1 q8..15
    __syncthreads();

    const int lbase = half * 512 + c32 * 16;    // per-lane LDS read base
    const size_t WBAND = (size_t)16 * H_ * 16;  // per-band W bytes per array

    #pragma unroll
    for (int s = 0; s < 8; s++) {
        const int cur = s & 1;
        const int nxt = cur ^ 1;

        // ---- prefetch band s+1 W FIRST: 4 gll16 -> other LDS buffer.
        //      By the band-end barrier these are ~4 ks old => vmcnt(0)
        //      drain ~free.
        if (s < 7) {
            size_t wadd = (size_t)(s + 1) * WBAND;
            gll16(wsrc0 + wadd,       sW + nxt * 16384 + 0 * 4096 + ldst);
            gll16(wsrc0 + wadd + WQ8, sW + nxt * 16384 + 1 * 4096 + ldst);
            gll16(wsrc1 + wadd,       sW + nxt * 16384 + 2 * 4096 + ldst);
            gll16(wsrc1 + wadd + WQ8, sW + nxt * 16384 + 3 * 4096 + ldst);
        }

        // ---- 4 k-steps (K=32 each) from buf[cur]; A loaded JIT.
        //      4 ds_read + 4 global 16B feed 8 MFMA.
        #pragma unroll
        for (int ks = 0; ks < 4; ks++) {
            int off = cur * 16384 + ks * 2048 + lbase;   // q = ks*4 + 2j + half
            f16x8 wr0 = *(const f16x8*)&sW[off];                  // arr0 j0
            f16x8 wr1 = *(const f16x8*)&sW[off + 1024];           // arr0 j1
            f16x8 wi0 = *(const f16x8*)&sW[off + 8192];           // arr1 j0
            f16x8 wi1 = *(const f16x8*)&sW[off + 8192 + 1024];    // arr1 j1
            // j = 0
            f16x8 a00 = *(const f16x8*)pA;
            f16x8 a10 = *(const f16x8*)(pA + 512);
            pA += strA;
            // j = 1
            f16x8 a01 = *(const f16x8*)pA;
            f16x8 a11 = *(const f16x8*)(pA + 512);
            pA += strA;
            // swapped operands: D[h][m] += W^T[h][k] * xt[m][k]
            aR0 = __builtin_amdgcn_mfma_f32_32x32x16_f16(wr0, a00, aR0, 0, 0, 0);
            aI0 = __builtin_amdgcn_mfma_f32_32x32x16_f16(wi0, a00, aI0, 0, 0, 0);
            aR1 = __builtin_amdgcn_mfma_f32_32x32x16_f16(wr0, a10, aR1, 0, 0, 0);
            aI1 = __builtin_amdgcn_mfma_f32_32x32x16_f16(wi0, a10, aI1, 0, 0, 0);
            aR0 = __builtin_amdgcn_mfma_f32_32x32x16_f16(wr1, a01, aR0, 0, 0, 0);
            aI0 = __builtin_amdgcn_mfma_f32_32x32x16_f16(wi1, a01, aI0, 0, 0, 0);
            aR1 = __builtin_amdgcn_mfma_f32_32x32x16_f16(wr1, a11, aR1, 0, 0, 0);
            aI1 = __builtin_amdgcn_mfma_f32_32x32x16_f16(wi1, a11, aI1, 0, 0, 0);
        }
        if (s < 7) __syncthreads();
    }

    // ---- epilogue: lane = one output row per sub-tile; regs = 16 h values.
    // acc IS t directly (f32 accumulate). br/bi loaded once, used by both
    // sub-tiles. Per sub-tile: in-lane sum then ONE shuffle.
    const int hbase = hs * 32 + 4 * half;
    float pr0 = 0.f, pi0 = 0.f, nr0 = 0.f, ni0 = 0.f;
    float pr1 = 0.f, pi1 = 0.f, nr1 = 0.f, ni1 = 0.f;
    #pragma unroll
    for (int reg = 0; reg < 16; reg++) {
        int h = hbase + (reg & 3) + 8 * (reg >> 2);
        float brv = br[h], biv = bi[h];
        float lr1, li1, lr2, li2;
        // sub-tile 0
        log_cosh_f(aR0[reg] + brv, aI0[reg] + biv, lr1, li1);
        log_cosh_f(brv - aR0[reg], biv - aI0[reg], lr2, li2);
        pr0 += lr1; pi0 += li1; nr0 += lr2; ni0 += li2;
        // sub-tile 1
        log_cosh_f(aR1[reg] + brv, aI1[reg] + biv, lr1, li1);
        log_cosh_f(brv - aR1[reg], biv - aI1[reg], lr2, li2);
        pr1 += lr1; pi1 += li1; nr1 += lr2; ni1 += li2;
    }
    pr0 += __shfl_xor(pr0, 32, 64);
    pi0 += __shfl_xor(pi0, 32, 64);
    nr0 += __shfl_xor(nr0, 32, 64);
    ni0 += __shfl_xor(ni0, 32, 64);
    pr1 += __shfl_xor(pr1, 32, 64);
    pi1 += __shfl_xor(pi1, 32, 64);
    nr1 += __shfl_xor(nr1, 32, 64);
    ni1 += __shfl_xor(ni1, 32, 64);
    if (half == 0) {
        // coalesced: 32 lanes write 512B; each (hs,row) written exactly once
        part[(size_t)hs * M_ + m0 + c32]      = make_float4(pr0, pi0, nr0, ni0);
        part[(size_t)hs * M_ + m0 + 32 + c32] = make_float4(pr1, pi1, nr1, ni1);
    }
}

// --- reduce the 128 h-slice partials per row ---
__global__ __launch_bounds__(64) void reduce_hb(
    const float4* __restrict__ part, float4* __restrict__ red)
{
    int row = blockIdx.x * 64 + threadIdx.x;
    float a0 = 0.f, a1 = 0.f, a2 = 0.f, a3 = 0.f;
    #pragma unroll 8
    for (int hb = 0; hb < NHB2_; hb++) {
        float4 v = part[(size_t)hb * M_ + row];
        a0 += v.x; a1 += v.y; a2 += v.z; a3 += v.w;
    }
    red[row] = make_float4(a0, a1, a2, a3);
}

// --- final logsumexp over 32 complex values per batch element ---
__global__ __launch_bounds__(64) void lse_final(
    const float4* __restrict__ red, float* __restrict__ out, int mode)
{
    int b = blockIdx.x * 64 + threadIdx.x;
    float re[32], im[32];
    #pragma unroll
    for (int t = 0; t < T_; t++) {
        float4 v = red[t * B_ + b];
        re[t]      = v.x; im[t]      = v.y;
        re[16 + t] = v.z; im[16 + t] = v.w;
    }
    float m = re[0];
    #pragma unroll
    for (int k = 1; k < 32; k++) m = fmaxf(m, re[k]);
    float Sr = 0.f, Si = 0.f;
    #pragma unroll
    for (int k = 0; k < 32; k++) {
        float mag = expf(re[k] - m);
        float s, c;
        sincosf(im[k], &s, &c);   // |im| can be tens of rad: libm reduction
        Sr = fmaf(mag, c, Sr);
        Si = fmaf(mag, s, Si);
    }
    float ore = 0.5f * logf(fmaf(Sr, Sr, Si * Si)) + m;
    float oim = atan2f(Si, Sr);
    if (mode == 0) out[b] = ore;
    else { out[b] = ore; out[B_ + b] = oim; }
}

// =======================================================================
// FALLBACK PATH — round-4 fp32 kernels (verified passing), used only if
// ws_size is too small for the packs.
// =======================================================================
#define FBM 128
#define FBH 64
#define FHC 4
#define FHBG (H_/(FBH*FHC))
#define FBK 16
#define FASTR 132
#define FPS (FHBG*M_)

__global__ __launch_bounds__(256, 3) void gemm_epi_fb(
    const float* __restrict__ x, const int* __restrict__ trans,
    const float* __restrict__ Wr, const float* __restrict__ Wi,
    const float* __restrict__ br, const float* __restrict__ bi,
    float* __restrict__ part)
{
    __shared__ float As[FBK * FASTR];
    __shared__ float Brs[FBK * FBH];
    __shared__ float Bis[FBK * FBH];

    const int tid = threadIdx.x;
    const int tx = tid & 15;
    const int ty = tid >> 4;
    const int hbg = blockIdx.x;
    const int m0 = blockIdx.y * FBM;
    const int t_band = m0 >> 10;
    const int* __restrict__ trow = trans + t_band * N_;

    float pr[8] = {}, pi[8] = {}, nr[8] = {}, ni[8] = {};

    for (int hc = 0; hc < FHC; hc++) {
        const int h0 = (hbg * FHC + hc) * FBH;
        float accre[8][4] = {}, accim[8][4] = {};
        for (int k0 = 0; k0 < N_; k0 += FBK) {
            #pragma unroll
            for (int p = 0; p < 8; p++) {
                int idx = tid + p * 256;
                int kk = idx & 15, r = idx >> 4;
                int b = (m0 + r) & (B_ - 1);
                As[kk * FASTR + r] = x[(size_t)b * N_ + trow[k0 + kk]];
            }
            {
                int r = tid >> 4, c4 = tid & 15;
                *(float4*)(Brs + r * FBH + c4 * 4) =
                    *(const float4*)(Wr + (size_t)(k0 + r) * H_ + h0 + c4 * 4);
                *(float4*)(Bis + r * FBH + c4 * 4) =
                    *(const float4*)(Wi + (size_t)(k0 + r) * H_ + h0 + c4 * 4);
            }
            __syncthreads();
            #pragma unroll
            for (int k = 0; k < FBK; k++) {
                float a[8], wr[4], wi[4];
                *(float4*)&a[0]  = *(float4*)&As[k * FASTR + ty * 8];
                *(float4*)&a[4]  = *(float4*)&As[k * FASTR + ty * 8 + 4];
                *(float4*)&wr[0] = *(float4*)&Brs[k * FBH + tx * 4];
                *(float4*)&wi[0] = *(float4*)&Bis[k * FBH + tx * 4];
                #pragma unroll
                for (int i = 0; i < 8; i++)
                    #pragma unroll
                    for (int j = 0; j < 4; j++) {
                        accre[i][j] = fmaf(a[i], wr[j], accre[i][j]);
                        accim[i][j] = fmaf(a[i], wi[j], accim[i][j]);
                    }
            }
            __syncthreads();
        }
        float brv[4], biv[4];
        #pragma unroll
        for (int j = 0; j < 4; j++) {
            brv[j] = br[h0 + tx * 4 + j];
            biv[j] = bi[h0 + tx * 4 + j];
        }
        #pragma unroll
        for (int i = 0; i < 8; i++)
            #pragma unroll
            for (int j = 0; j < 4; j++) {
                float tr = accre[i][j], ti = accim[i][j];
                float lr, li;
                log_cosh_c(tr + brv[j], ti + biv[j], lr, li);
                pr[i] += lr; pi[i] += li;
                log_cosh_c(brv[j] - tr, biv[j] - ti, lr, li);
                nr[i] += lr; ni[i] += li;
            }
    }
    #pragma unroll
    for (int i = 0; i < 8; i++) {
        float a0 = pr[i], a1 = pi[i], a2 = nr[i], a3 = ni[i];
        #pragma unroll
        for (int off = 1; off < 16; off <<= 1) {
            a0 += __shfl_xor(a0, off, 64);
            a1 += __shfl_xor(a1, off, 64);
            a2 += __shfl_xor(a2, off, 64);
            a3 += __shfl_xor(a3, off, 64);
        }
        if (tx == 0) {
            int row = m0 + ty * 8 + i;
            part[0 * FPS + hbg * M_ + row] = a0;
            part[1 * FPS + hbg * M_ + row] = a1;
            part[2 * FPS + hbg * M_ + row] = a2;
            part[3 * FPS + hbg * M_ + row] = a3;
        }
    }
}

__global__ __launch_bounds__(256) void sum_lse_fb(
    const float* __restrict__ part, float* __restrict__ out, int mode)
{
    int b = blockIdx.x * 256 + threadIdx.x;
    float re[32], im[32];
    #pragma unroll
    for (int t = 0; t < T_; t++) {
        int row = t * B_ + b;
        float a0 = 0.f, a1 = 0.f, a2 = 0.f, a3 = 0.f;
        for (int hb = 0; hb < FHBG; hb++) {
            a0 += part[0 * FPS + hb * M_ + row];
            a1 += part[1 * FPS + hb * M_ + row];
            a2 += part[2 * FPS + hb * M_ + row];
            a3 += part[3 * FPS + hb * M_ + row];
        }
        re[t]      = a0; im[t]      = a1;
        re[16 + t] = a2; im[16 + t] = a3;
    }
    float m = re[0];
    #pragma unroll
    for (int k = 1; k < 32; k++) m = fmaxf(m, re[k]);
    float Sr = 0.f, Si = 0.f;
    #pragma unroll
    for (int k = 0; k < 32; k++) {
        float mag = expf(re[k] - m);
        float s, c;
        sincosf(im[k], &s, &c);
        Sr = fmaf(mag, c, Sr);
        Si = fmaf(mag, s, Si);
    }
    float ore = 0.5f * logf(fmaf(Sr, Sr, Si * Si)) + m;
    float oim = atan2f(Si, Sr);
    if (mode == 0) out[b] = ore;
    else { out[b] = ore; out[B_ + b] = oim; }
}

// =======================================================================

extern "C" void kernel_launch(void* const* d_in, const int* in_sizes, int n_in,
                              void* d_out, int out_size, void* d_ws, size_t ws_size,
                              hipStream_t stream) {
    const float *x = nullptr, *Wr = nullptr, *Wi = nullptr, *br = nullptr, *bi = nullptr;
    const int *trans = nullptr;
    for (int i = 0; i < n_in; i++) {
        int s = in_sizes[i];
        if (s == B_ * N_ && !x)            x  = (const float*)d_in[i];
        else if (s == N_ * H_)             { if (!Wr) Wr = (const float*)d_in[i];
                                             else if (!Wi) Wi = (const float*)d_in[i]; }
        else if (s == H_)                  { if (!br) br = (const float*)d_in[i];
                                             else if (!bi) bi = (const float*)d_in[i]; }
        else if (s == T_ * N_ && !trans)   trans = (const int*)d_in[i];
    }
    if (!x)     x     = (const float*)d_in[0];
    if (!Wr)    Wr    = (const float*)d_in[1];
    if (!Wi)    Wi    = (const float*)d_in[2];
    if (!br)    br    = (const float*)d_in[3];
    if (!bi)    bi    = (const float*)d_in[4];
    if (!trans) trans = (const int*)d_in[5];

    float* out = (float*)d_out;
    const int mode = (out_size == B_) ? 0 : 1;

    const size_t NEED = (size_t)2 * M_ * N_          // A16 (f16)
                      + (size_t)4 * N_ * H_          // Wr16+Wi16 (f16)
                      + (size_t)NHB2_ * M_ * 16      // float4 partials
                      + (size_t)M_ * 16;             // float4 reduced

    if (ws_size >= NEED) {
        signed char* A16  = (signed char*)d_ws;
        signed char* Wr16 = A16  + (size_t)2 * M_ * N_;
        signed char* Wi16 = Wr16 + (size_t)2 * N_ * H_;
        float4* part = (float4*)(Wi16 + (size_t)2 * N_ * H_);
        float4* red  = part + (size_t)NHB2_ * M_;

        prep_A16<<<(M_ * (N_ / 8)) / 256, 256, 0, stream>>>(x, trans, A16);
        dim3 gw((N_ / 8) * H_ / 256, 2);
        prep_W16<<<gw, 256, 0, stream>>>(Wr, Wi, Wr16, Wi16);
        gemm_f16<<<64 * 128, 256, 0, stream>>>(A16, Wr16, Wi16,
                                               br, bi, part);
        reduce_hb<<<M_ / 64, 64, 0, stream>>>(part, red);
        lse_final<<<B_ / 64, 64, 0, stream>>>(red, out, mode);
    } else {
        float* part = (float*)d_ws;
        dim3 grid(FHBG, M_ / FBM);
        gemm_epi_fb<<<grid, 256, 0, stream>>>(x, trans, Wr, Wi, br, bi, part);
        sum_lse_fb<<<B_ / 256, 256, 0, stream>>>(part, out, mode);
    }
}